// Round 2
// baseline (487.684 us; speedup 1.0000x reference)
//
#include <hip/hip_runtime.h>
#include <stdint.h>

typedef __attribute__((ext_vector_type(4))) float f32x4;
typedef __attribute__((ext_vector_type(8))) _Float16 h8;
typedef __attribute__((ext_vector_type(4))) float f4v;
typedef __attribute__((ext_vector_type(4))) _Float16 h4v;

#define B_ 4
#define T_ 2048
#define C_ 1024
#define NH 16
#define HD 64
#define M_ (B_*T_)   // 8192
#define KD 1024      // reduction dim of all GEMMs

// async global->LDS, 16B per lane; LDS dest must be wave-uniform base (HW adds lane*16)
#define GL2LDS16(g, l) \
  __builtin_amdgcn_global_load_lds((const __attribute__((address_space(1))) unsigned int*)(g), \
      (__attribute__((address_space(3))) unsigned int*)(unsigned int)(uintptr_t)(l), 16, 0, 0)

__global__ void cast_x_kernel(const float* __restrict__ src, _Float16* __restrict__ dst, int n4) {
  int i = blockIdx.x * blockDim.x + threadIdx.x;
  if (i < n4) {
    f4v v = ((const f4v*)src)[i];
    ((h4v*)dst)[i] = __builtin_convertvector(v, h4v);
  }
}

// Stage a 128x32 fp32 tile (rows stride KD) into fp16 LDS [128][32], row-major.
// Per wave: 2 halves x (2 float4 loads + cvt + 1 ds_write_b128).
__device__ __forceinline__ void stage_f32_128x32(const float* src, _Float16* dst, int lane, int wav) {
  #pragma unroll
  for (int hh = 0; hh < 2; hh++) {
    int row = hh*64 + wav*16 + (lane >> 2);
    int colf = (lane & 3) * 8;
    const float* p = src + (size_t)row * KD + colf;
    f4v a = *(const f4v*)p;
    f4v b = *(const f4v*)(p + 4);
    h8 v;
    v[0]=(_Float16)a[0]; v[1]=(_Float16)a[1]; v[2]=(_Float16)a[2]; v[3]=(_Float16)a[3];
    v[4]=(_Float16)b[0]; v[5]=(_Float16)b[1]; v[6]=(_Float16)b[2]; v[7]=(_Float16)b[3];
    *(h8*)(dst + row*32 + colf) = v;
  }
}

// ---------------- QKV GEMM: Out[M][N] = A[M][K] * W[N][K]^T + bias, 128x128 tile, BK=32 ----------------
// 256 threads = 4 waves in 2x2 grid, each wave 64x64 = 4x4 fragments of 16x16x32 MFMA.
// AMODE 0: A from fp16 buffer via global_load_lds.  AMODE 1: A from fp32 x via reg-cvt staging.
template<int AMODE>
__global__ __launch_bounds__(256) void gemm_qkv_kernel(
    const _Float16* __restrict__ Xh, const float* __restrict__ Xf,
    const float* __restrict__ Wq, const float* __restrict__ Wk, const float* __restrict__ Wv,
    const float* __restrict__ bq, const float* __restrict__ bk, const float* __restrict__ bv,
    _Float16* __restrict__ Qo, _Float16* __restrict__ Ko, _Float16* __restrict__ Vo)
{
  __shared__ _Float16 As[128*32];
  __shared__ _Float16 Bs[128*32];
  int tid = threadIdx.x;
  int lane = tid & 63, wav = tid >> 6;
  int mb = blockIdx.x;
  int nbg = blockIdx.y;
  int sel = nbg >> 3, nb = nbg & 7;
  const float* W = sel == 0 ? Wq : (sel == 1 ? Wk : Wv);
  const float* bias = sel == 0 ? bq : (sel == 1 ? bk : bv);
  _Float16* Out = sel == 0 ? Qo : (sel == 1 ? Ko : Vo);
  int m0 = mb * 128, n0 = nb * 128;

  f32x4 acc[4][4] = {};

  int r_in = lane >> 2;          // 0..15 row within 16-row chunk
  int c8   = (lane & 3) * 8;     // k-element offset 0,8,16,24
  int l15 = lane & 15, l4 = lane >> 4;
  int wr = (wav >> 1) * 64, wc = (wav & 1) * 64;

  for (int k0 = 0; k0 < KD; k0 += 32) {
    if (AMODE == 0) {
      GL2LDS16(Xh + (size_t)(m0 +      wav*16 + r_in)*KD + k0 + c8, As +        wav*512);
      GL2LDS16(Xh + (size_t)(m0 + 64 + wav*16 + r_in)*KD + k0 + c8, As + 2048 + wav*512);
    } else {
      stage_f32_128x32(Xf + (size_t)m0 * KD + k0, As, lane, wav);
    }
    stage_f32_128x32(W + (size_t)n0 * KD + k0, Bs, lane, wav);
    __syncthreads();

    h8 af[4], bf[4];
    #pragma unroll
    for (int f = 0; f < 4; f++) {
      af[f] = *(const h8*)(As + (wr + f*16 + l15)*32 + l4*8);
      bf[f] = *(const h8*)(Bs + (wc + f*16 + l15)*32 + l4*8);
    }
    #pragma unroll
    for (int i = 0; i < 4; i++)
      #pragma unroll
      for (int j = 0; j < 4; j++)
        acc[i][j] = __builtin_amdgcn_mfma_f32_16x16x32_f16(af[i], bf[j], acc[i][j], 0, 0, 0);
    __syncthreads();
  }

  #pragma unroll
  for (int i = 0; i < 4; i++) {
    int mrow = m0 + wr + i*16 + l4*4;
    #pragma unroll
    for (int j = 0; j < 4; j++) {
      int ncol = n0 + wc + j*16 + l15;
      float bval = bias[ncol];
      #pragma unroll
      for (int r = 0; r < 4; r++)
        Out[(size_t)(mrow + r)*C_ + ncol] = (_Float16)(acc[i][j][r] + bval);
    }
  }
}

// ---------------- Output projection: Out[M][N] = A[M][K](fp16) * W[N][K]^T(fp32) + bias, clamp ±10 ----------------
__global__ __launch_bounds__(256) void gemm_proj_kernel(
    const _Float16* __restrict__ A, const float* __restrict__ W,
    const float* __restrict__ bias, float* __restrict__ Out)
{
  __shared__ _Float16 As[128*32];
  __shared__ _Float16 Bs[128*32];
  int tid = threadIdx.x;
  int lane = tid & 63, wav = tid >> 6;
  int m0 = blockIdx.x * 128, n0 = blockIdx.y * 128;

  f32x4 acc[4][4] = {};
  int r_in = lane >> 2;
  int c8   = (lane & 3) * 8;
  int l15 = lane & 15, l4 = lane >> 4;
  int wr = (wav >> 1) * 64, wc = (wav & 1) * 64;

  for (int k0 = 0; k0 < KD; k0 += 32) {
    GL2LDS16(A + (size_t)(m0 +      wav*16 + r_in)*KD + k0 + c8, As +        wav*512);
    GL2LDS16(A + (size_t)(m0 + 64 + wav*16 + r_in)*KD + k0 + c8, As + 2048 + wav*512);
    stage_f32_128x32(W + (size_t)n0 * KD + k0, Bs, lane, wav);
    __syncthreads();

    h8 af[4], bf[4];
    #pragma unroll
    for (int f = 0; f < 4; f++) {
      af[f] = *(const h8*)(As + (wr + f*16 + l15)*32 + l4*8);
      bf[f] = *(const h8*)(Bs + (wc + f*16 + l15)*32 + l4*8);
    }
    #pragma unroll
    for (int i = 0; i < 4; i++)
      #pragma unroll
      for (int j = 0; j < 4; j++)
        acc[i][j] = __builtin_amdgcn_mfma_f32_16x16x32_f16(af[i], bf[j], acc[i][j], 0, 0, 0);
    __syncthreads();
  }

  #pragma unroll
  for (int i = 0; i < 4; i++) {
    int mrow = m0 + wr + i*16 + l4*4;
    #pragma unroll
    for (int j = 0; j < 4; j++) {
      int ncol = n0 + wc + j*16 + l15;
      float bval = bias[ncol];
      #pragma unroll
      for (int r = 0; r < 4; r++) {
        float v = acc[i][j][r] + bval;
        v = fminf(10.f, fmaxf(-10.f, v));
        Out[(size_t)(mrow + r)*C_ + ncol] = v;
      }
    }
  }
}

// ---------------- Flash attention, causal. Block = (64 q rows, head, batch); wave = 16 q rows. ----------------
// O may alias Q (in-place): each wave hoists its own 16 rows x 64 cols of Q into registers
// before any O write, and blocks/waves touch disjoint (row, head) territory.
__global__ __launch_bounds__(256) void attn_kernel(
    const _Float16* Q, const _Float16* __restrict__ K,
    const _Float16* __restrict__ V, _Float16* O)
{
  __shared__ _Float16 Vt[HD * 32];         // [d][key] transposed V block
  __shared__ _Float16 Plds[4][16 * 32];    // per-wave P[q][key]
  int tid = threadIdx.x;
  int lane = tid & 63, w = tid >> 6;
  int qi = blockIdx.x, h = blockIdx.y, b = blockIdx.z;
  int l15 = lane & 15, l4 = lane >> 4;

  // Q fragments (hoisted): row = l15, d-halves 0..31 / 32..63
  const _Float16* qbase = Q + (size_t)(b*T_ + qi*64 + w*16 + l15)*C_ + h*HD;
  h8 qf0 = *(const h8*)(qbase + l4*8);
  h8 qf1 = *(const h8*)(qbase + 32 + l4*8);

  f32x4 acc[4] = {};
  float mrow[4] = {-INFINITY, -INFINITY, -INFINITY, -INFINITY};
  float lrow[4] = {0.f, 0.f, 0.f, 0.f};

  int nkeys = qi*64 + 64;          // block-uniform causal bound
  int vr = tid >> 3;               // 0..31: V stage row
  int vc = (tid & 7) * 8;          // V stage col offset

  for (int kb = 0; kb < nkeys; kb += 32) {
    __syncthreads();               // prev PV reads done before overwrite
    // stage V^T cooperatively: Vt[d][key]
    {
      h8 vv = *(const h8*)(V + (size_t)(b*T_ + kb + vr)*C_ + h*HD + vc);
      #pragma unroll
      for (int j = 0; j < 8; j++) Vt[(vc + j)*32 + vr] = vv[j];
    }
    // S = Q*K^T for 32 keys (two 16-key tiles), K frags straight from global (L2-resident)
    const _Float16* kbase = K + (size_t)(b*T_ + kb)*C_ + h*HD;
    f32x4 s0 = {}, s1 = {};
    {
      h8 kf0 = *(const h8*)(kbase + (size_t)l15*C_ + l4*8);
      h8 kf1 = *(const h8*)(kbase + (size_t)l15*C_ + 32 + l4*8);
      s0 = __builtin_amdgcn_mfma_f32_16x16x32_f16(qf0, kf0, s0, 0, 0, 0);
      s0 = __builtin_amdgcn_mfma_f32_16x16x32_f16(qf1, kf1, s0, 0, 0, 0);
      h8 kf2 = *(const h8*)(kbase + (size_t)(16 + l15)*C_ + l4*8);
      h8 kf3 = *(const h8*)(kbase + (size_t)(16 + l15)*C_ + 32 + l4*8);
      s1 = __builtin_amdgcn_mfma_f32_16x16x32_f16(qf0, kf2, s1, 0, 0, 0);
      s1 = __builtin_amdgcn_mfma_f32_16x16x32_f16(qf1, kf3, s1, 0, 0, 0);
    }
    int qg = qi*64 + w*16 + l4*4;      // + i gives this reg's query row
    int kg0 = kb + l15, kg1 = kb + 16 + l15;
    float alpha[4];
    #pragma unroll
    for (int i = 0; i < 4; i++) {
      float a = s0[i] * 0.125f;
      float c = s1[i] * 0.125f;
      if (kg0 > qg + i) a = -INFINITY;
      if (kg1 > qg + i) c = -INFINITY;
      float mx = fmaxf(a, c);
      mx = fmaxf(mx, __shfl_xor(mx, 1, 16));
      mx = fmaxf(mx, __shfl_xor(mx, 2, 16));
      mx = fmaxf(mx, __shfl_xor(mx, 4, 16));
      mx = fmaxf(mx, __shfl_xor(mx, 8, 16));
      float mn = fmaxf(mrow[i], mx);
      alpha[i] = __expf(mrow[i] - mn);
      mrow[i] = mn;
      float p0 = __expf(a - mn);
      float p1 = __expf(c - mn);
      float rs = p0 + p1;
      rs += __shfl_xor(rs, 1, 16);
      rs += __shfl_xor(rs, 2, 16);
      rs += __shfl_xor(rs, 4, 16);
      rs += __shfl_xor(rs, 8, 16);
      lrow[i] = lrow[i]*alpha[i] + rs;
      Plds[w][(l4*4 + i)*32 + l15]      = (_Float16)p0;
      Plds[w][(l4*4 + i)*32 + 16 + l15] = (_Float16)p1;
    }
    #pragma unroll
    for (int c2 = 0; c2 < 4; c2++) {
      acc[c2][0] *= alpha[0]; acc[c2][1] *= alpha[1];
      acc[c2][2] *= alpha[2]; acc[c2][3] *= alpha[3];
    }
    __syncthreads();               // Vt + P visible
    // O += P * V
    h8 pa = *(const h8*)(&Plds[w][l15*32 + l4*8]);
    #pragma unroll
    for (int c2 = 0; c2 < 4; c2++) {
      h8 vf = *(const h8*)(&Vt[(c2*16 + l15)*32 + l4*8]);
      acc[c2] = __builtin_amdgcn_mfma_f32_16x16x32_f16(pa, vf, acc[c2], 0, 0, 0);
    }
  }

  #pragma unroll
  for (int c2 = 0; c2 < 4; c2++) {
    #pragma unroll
    for (int i = 0; i < 4; i++) {
      float v = acc[c2][i] / lrow[i];
      v = fminf(10.f, fmaxf(-10.f, v));
      O[(size_t)(b*T_ + qi*64 + w*16 + l4*4 + i)*C_ + h*HD + c2*16 + l15] = (_Float16)v;
    }
  }
}

extern "C" void kernel_launch(void* const* d_in, const int* in_sizes, int n_in,
                              void* d_out, int out_size, void* d_ws, size_t ws_size,
                              hipStream_t stream) {
  (void)in_sizes; (void)n_in; (void)out_size;
  const float* x  = (const float*)d_in[0];
  const float* wq = (const float*)d_in[1];
  const float* bq = (const float*)d_in[2];
  const float* wk = (const float*)d_in[3];
  const float* bk = (const float*)d_in[4];
  const float* wv = (const float*)d_in[5];
  const float* bv = (const float*)d_in[6];
  const float* wp = (const float*)d_in[7];
  const float* bp = (const float*)d_in[8];
  float* out = (float*)d_out;

  char* ws = (char*)d_ws;
  const size_t MB = 1ull << 20;
  _Float16* qh = (_Float16*)(ws + 0*MB);    // 16 MB; attention output written in place
  _Float16* kh = (_Float16*)(ws + 16*MB);   // 16 MB
  _Float16* vh = (_Float16*)(ws + 32*MB);   // 16 MB
  _Float16* xh = (_Float16*)(ws + 48*MB);   // 16 MB (only if ws_size >= 64 MB)

  bool use_xh = ws_size >= 64*MB;
  if (use_xh) {
    cast_x_kernel<<<dim3((M_*C_/4) / 256), 256, 0, stream>>>(x, xh, M_*C_/4);
    gemm_qkv_kernel<0><<<dim3(M_/128, 24), 256, 0, stream>>>(
        xh, nullptr, wq, wk, wv, bq, bk, bv, qh, kh, vh);
  } else {
    gemm_qkv_kernel<1><<<dim3(M_/128, 24), 256, 0, stream>>>(
        nullptr, x, wq, wk, wv, bq, bk, bv, qh, kh, vh);
  }
  attn_kernel<<<dim3(T_/64, NH, B_), 256, 0, stream>>>(qh, kh, vh, qh);
  gemm_proj_kernel<<<dim3(M_/128, C_/128), 256, 0, stream>>>(qh, wp, bp, out);
}

// Round 3
// 346.671 us; speedup vs baseline: 1.4068x; 1.4068x over previous
//
#include <hip/hip_runtime.h>
#include <stdint.h>

typedef __attribute__((ext_vector_type(4))) float f32x4;
typedef __attribute__((ext_vector_type(8))) _Float16 h8;
typedef __attribute__((ext_vector_type(4))) float f4v;
typedef __attribute__((ext_vector_type(4))) _Float16 h4v;

#define B_ 4
#define T_ 2048
#define C_ 1024
#define NH 16
#define HD 64
#define M_ (B_*T_)   // 8192
#define KD 1024      // reduction dim of all GEMMs

#define MFMA16(a, b, c) __builtin_amdgcn_mfma_f32_16x16x32_f16(a, b, c, 0, 0, 0)

// async global->LDS, 16B per lane; LDS dest must be wave-uniform base (HW adds lane*16)
#define GL2LDS16(g, l) \
  __builtin_amdgcn_global_load_lds((const __attribute__((address_space(1))) unsigned int*)(g), \
      (__attribute__((address_space(3))) unsigned int*)(unsigned int)(uintptr_t)(l), 16, 0, 0)

__global__ void cast_x_kernel(const float* __restrict__ src, _Float16* __restrict__ dst, int n4) {
  int i = blockIdx.x * blockDim.x + threadIdx.x;
  if (i < n4) {
    f4v v = ((const f4v*)src)[i];
    ((h4v*)dst)[i] = __builtin_convertvector(v, h4v);
  }
}

// Stage a 128x32 fp32 tile (rows stride KD) into fp16 LDS [128][32], row-major.
__device__ __forceinline__ void stage_f32_128x32(const float* src, _Float16* dst, int lane, int wav) {
  #pragma unroll
  for (int hh = 0; hh < 2; hh++) {
    int row = hh*64 + wav*16 + (lane >> 2);
    int colf = (lane & 3) * 8;
    const float* p = src + (size_t)row * KD + colf;
    f4v a = *(const f4v*)p;
    f4v b = *(const f4v*)(p + 4);
    h8 v;
    v[0]=(_Float16)a[0]; v[1]=(_Float16)a[1]; v[2]=(_Float16)a[2]; v[3]=(_Float16)a[3];
    v[4]=(_Float16)b[0]; v[5]=(_Float16)b[1]; v[6]=(_Float16)b[2]; v[7]=(_Float16)b[3];
    *(h8*)(dst + row*32 + colf) = v;
  }
}

// ---------------- QKV GEMM: Out[M][N] = A[M][K] * W[N][K]^T + bias, 128x128 tile, BK=32 ----------------
// sel==2 (V) is written TRANSPOSED as Vt[b][h][d][t] so attention needs no LDS transpose.
template<int AMODE>
__global__ __launch_bounds__(256) void gemm_qkv_kernel(
    const _Float16* __restrict__ Xh, const float* __restrict__ Xf,
    const float* __restrict__ Wq, const float* __restrict__ Wk, const float* __restrict__ Wv,
    const float* __restrict__ bq, const float* __restrict__ bk, const float* __restrict__ bv,
    _Float16* __restrict__ Qo, _Float16* __restrict__ Ko, _Float16* __restrict__ Vo)
{
  __shared__ _Float16 As[128*32];
  __shared__ _Float16 Bs[128*32];
  int tid = threadIdx.x;
  int lane = tid & 63, wav = tid >> 6;
  int mb = blockIdx.x;
  int nbg = blockIdx.y;
  int sel = nbg >> 3, nb = nbg & 7;
  const float* W = sel == 0 ? Wq : (sel == 1 ? Wk : Wv);
  const float* bias = sel == 0 ? bq : (sel == 1 ? bk : bv);
  _Float16* Out = sel == 0 ? Qo : (sel == 1 ? Ko : Vo);
  int m0 = mb * 128, n0 = nb * 128;

  f32x4 acc[4][4] = {};

  int r_in = lane >> 2;          // 0..15 row within 16-row chunk
  int c8   = (lane & 3) * 8;     // k-element offset 0,8,16,24
  int l15 = lane & 15, l4 = lane >> 4;
  int wr = (wav >> 1) * 64, wc = (wav & 1) * 64;

  for (int k0 = 0; k0 < KD; k0 += 32) {
    if (AMODE == 0) {
      GL2LDS16(Xh + (size_t)(m0 +      wav*16 + r_in)*KD + k0 + c8, As +        wav*512);
      GL2LDS16(Xh + (size_t)(m0 + 64 + wav*16 + r_in)*KD + k0 + c8, As + 2048 + wav*512);
    } else {
      stage_f32_128x32(Xf + (size_t)m0 * KD + k0, As, lane, wav);
    }
    stage_f32_128x32(W + (size_t)n0 * KD + k0, Bs, lane, wav);
    __syncthreads();

    h8 af[4], bf[4];
    #pragma unroll
    for (int f = 0; f < 4; f++) {
      af[f] = *(const h8*)(As + (wr + f*16 + l15)*32 + l4*8);
      bf[f] = *(const h8*)(Bs + (wc + f*16 + l15)*32 + l4*8);
    }
    #pragma unroll
    for (int i = 0; i < 4; i++)
      #pragma unroll
      for (int j = 0; j < 4; j++)
        acc[i][j] = MFMA16(af[i], bf[j], acc[i][j]);
    __syncthreads();
  }

  if (sel == 2) {
    // transposed V epilogue: Vt[((b*NH+h)*HD+d)*T_ + t], 4 consecutive t per reg quad
    #pragma unroll
    for (int i = 0; i < 4; i++) {
      int mrow = m0 + wr + i*16 + l4*4;
      int bb = mrow >> 11, t = mrow & 2047;
      #pragma unroll
      for (int j = 0; j < 4; j++) {
        int ncol = n0 + wc + j*16 + l15;
        float bval = bias[ncol];
        int hh = ncol >> 6, d = ncol & 63;
        h4v v;
        #pragma unroll
        for (int r = 0; r < 4; r++) v[r] = (_Float16)(acc[i][j][r] + bval);
        *(h4v*)(Vo + ((size_t)(bb*NH + hh)*HD + d)*T_ + t) = v;
      }
    }
  } else {
    #pragma unroll
    for (int i = 0; i < 4; i++) {
      int mrow = m0 + wr + i*16 + l4*4;
      #pragma unroll
      for (int j = 0; j < 4; j++) {
        int ncol = n0 + wc + j*16 + l15;
        float bval = bias[ncol];
        #pragma unroll
        for (int r = 0; r < 4; r++)
          Out[(size_t)(mrow + r)*C_ + ncol] = (_Float16)(acc[i][j][r] + bval);
      }
    }
  }
}

// ---------------- Output projection: Out[M][N] = A[M][K](fp16) * W[N][K]^T(fp32) + bias, clamp ±10 ----------------
__global__ __launch_bounds__(256) void gemm_proj_kernel(
    const _Float16* __restrict__ A, const float* __restrict__ W,
    const float* __restrict__ bias, float* __restrict__ Out)
{
  __shared__ _Float16 As[128*32];
  __shared__ _Float16 Bs[128*32];
  int tid = threadIdx.x;
  int lane = tid & 63, wav = tid >> 6;
  int m0 = blockIdx.x * 128, n0 = blockIdx.y * 128;

  f32x4 acc[4][4] = {};
  int r_in = lane >> 2;
  int c8   = (lane & 3) * 8;
  int l15 = lane & 15, l4 = lane >> 4;
  int wr = (wav >> 1) * 64, wc = (wav & 1) * 64;

  for (int k0 = 0; k0 < KD; k0 += 32) {
    GL2LDS16(A + (size_t)(m0 +      wav*16 + r_in)*KD + k0 + c8, As +        wav*512);
    GL2LDS16(A + (size_t)(m0 + 64 + wav*16 + r_in)*KD + k0 + c8, As + 2048 + wav*512);
    stage_f32_128x32(W + (size_t)n0 * KD + k0, Bs, lane, wav);
    __syncthreads();

    h8 af[4], bf[4];
    #pragma unroll
    for (int f = 0; f < 4; f++) {
      af[f] = *(const h8*)(As + (wr + f*16 + l15)*32 + l4*8);
      bf[f] = *(const h8*)(Bs + (wc + f*16 + l15)*32 + l4*8);
    }
    #pragma unroll
    for (int i = 0; i < 4; i++)
      #pragma unroll
      for (int j = 0; j < 4; j++)
        acc[i][j] = MFMA16(af[i], bf[j], acc[i][j]);
    __syncthreads();
  }

  #pragma unroll
  for (int i = 0; i < 4; i++) {
    int mrow = m0 + wr + i*16 + l4*4;
    #pragma unroll
    for (int j = 0; j < 4; j++) {
      int ncol = n0 + wc + j*16 + l15;
      float bval = bias[ncol];
      #pragma unroll
      for (int r = 0; r < 4; r++) {
        float v = acc[i][j][r] + bval;
        v = fminf(10.f, fmaxf(-10.f, v));
        Out[(size_t)(mrow + r)*C_ + ncol] = v;
      }
    }
  }
}

// ---------------- Flash attention, causal, barrier-free. ----------------
// Block = q-tile PAIR (p, 31-p) x head x batch -> uniform ~2112 keys/block.
// 4 independent waves, 16 q rows each. Swapped QK^T (S^T = K*Q^T) makes q lane-local.
// V is pre-transposed in global (Vt[b][h][d][t]) -> PV B-frags are direct 16B loads.
// O overwrites Q in place (each wave's rows/head-slice are exclusively its own).
__global__ __launch_bounds__(256, 4) void attn_kernel(
    const _Float16* Q, const _Float16* __restrict__ K,
    const _Float16* __restrict__ Vt, _Float16* O)
{
  __shared__ _Float16 Plds[4][16*40];    // per-wave P, row stride 40 (pad: bank-conflict-free)
  int tid = threadIdx.x;
  int lane = tid & 63, w = tid >> 6;
  int p = blockIdx.x, h = blockIdx.y, b = blockIdx.z;
  int l15 = lane & 15, l4 = lane >> 4;
  _Float16* Pl = &Plds[w][0];
  const _Float16* Kbh = K + (size_t)b*T_*C_ + h*HD;
  const _Float16* Vbh = Vt + (size_t)(b*NH + h)*HD*T_;

  #pragma unroll 1
  for (int half = 0; half < 2; half++) {
    int qt = half ? (31 - p) : p;
    int q0 = qt*64 + w*16;
    int q = q0 + l15;

    const _Float16* qbase = Q + (size_t)(b*T_ + q)*C_ + h*HD;
    h8 qf0 = *(const h8*)(qbase + l4*8);
    h8 qf1 = *(const h8*)(qbase + 32 + l4*8);

    f32x4 acc[4] = {};
    float mrow = -INFINITY, lrow = 0.f;
    int last = ((q0 + 15) >> 5) << 5;   // final kv-step; only this one needs masking

    h8 kf0 = *(const h8*)(Kbh + (size_t)l15*C_ + l4*8);
    h8 kf1 = *(const h8*)(Kbh + (size_t)l15*C_ + 32 + l4*8);
    h8 kf2 = *(const h8*)(Kbh + (size_t)(16 + l15)*C_ + l4*8);
    h8 kf3 = *(const h8*)(Kbh + (size_t)(16 + l15)*C_ + 32 + l4*8);

    #pragma unroll 1
    for (int kb = 0; kb <= last; kb += 32) {
      f32x4 s0 = {}, s1 = {};
      s0 = MFMA16(kf0, qf0, s0);
      s0 = MFMA16(kf1, qf1, s0);
      s1 = MFMA16(kf2, qf0, s1);
      s1 = MFMA16(kf3, qf1, s1);

      if (kb < last) {       // register-prefetch next K tile
        const _Float16* kn = Kbh + (size_t)(kb + 32)*C_;
        kf0 = *(const h8*)(kn + (size_t)l15*C_ + l4*8);
        kf1 = *(const h8*)(kn + (size_t)l15*C_ + 32 + l4*8);
        kf2 = *(const h8*)(kn + (size_t)(16 + l15)*C_ + l4*8);
        kf3 = *(const h8*)(kn + (size_t)(16 + l15)*C_ + 32 + l4*8);
      }
      // V^T fragments for this key block (independent loads, in flight during softmax)
      h8 vf0 = *(const h8*)(Vbh + (size_t)(l15     )*T_ + kb + l4*8);
      h8 vf1 = *(const h8*)(Vbh + (size_t)(16 + l15)*T_ + kb + l4*8);
      h8 vf2 = *(const h8*)(Vbh + (size_t)(32 + l15)*T_ + kb + l4*8);
      h8 vf3 = *(const h8*)(Vbh + (size_t)(48 + l15)*T_ + kb + l4*8);

      float sc[8];
      #pragma unroll
      for (int j = 0; j < 4; j++) { sc[j] = s0[j]*0.125f; sc[4+j] = s1[j]*0.125f; }
      if (kb == last) {
        #pragma unroll
        for (int r = 0; r < 4; r++) {
          if (kb      + l4*4 + r > q) sc[r]   = -INFINITY;
          if (kb + 16 + l4*4 + r > q) sc[4+r] = -INFINITY;
        }
      }
      float mx = sc[0];
      #pragma unroll
      for (int j = 1; j < 8; j++) mx = fmaxf(mx, sc[j]);
      mx = fmaxf(mx, __shfl_xor(mx, 16));
      mx = fmaxf(mx, __shfl_xor(mx, 32));
      float mn = fmaxf(mrow, mx);
      float alpha = __expf(mrow - mn);
      mrow = mn;
      float ls = 0.f;
      h4v pw0, pw1;
      #pragma unroll
      for (int j = 0; j < 4; j++) {
        float e0 = __expf(sc[j]   - mn); ls += e0; pw0[j] = (_Float16)e0;
        float e1 = __expf(sc[4+j] - mn); ls += e1; pw1[j] = (_Float16)e1;
      }
      ls += __shfl_xor(ls, 16);
      ls += __shfl_xor(ls, 32);
      lrow = lrow*alpha + ls;

      *(h4v*)(Pl + l15*40 +      l4*4) = pw0;
      *(h4v*)(Pl + l15*40 + 16 + l4*4) = pw1;

      float av[4];
      #pragma unroll
      for (int r = 0; r < 4; r++) av[r] = __shfl(alpha, l4*4 + r);
      #pragma unroll
      for (int c2 = 0; c2 < 4; c2++) {
        acc[c2][0] *= av[0]; acc[c2][1] *= av[1];
        acc[c2][2] *= av[2]; acc[c2][3] *= av[3];
      }

      h8 pa = *(const h8*)(Pl + l15*40 + l4*8);
      acc[0] = MFMA16(pa, vf0, acc[0]);
      acc[1] = MFMA16(pa, vf1, acc[1]);
      acc[2] = MFMA16(pa, vf2, acc[2]);
      acc[3] = MFMA16(pa, vf3, acc[3]);
    }

    float lr[4];
    #pragma unroll
    for (int r = 0; r < 4; r++) lr[r] = __shfl(lrow, l4*4 + r);
    #pragma unroll
    for (int c2 = 0; c2 < 4; c2++) {
      #pragma unroll
      for (int r = 0; r < 4; r++) {
        float v = acc[c2][r] / lr[r];
        v = fminf(10.f, fmaxf(-10.f, v));
        O[(size_t)(b*T_ + q0 + l4*4 + r)*C_ + h*HD + c2*16 + l15] = (_Float16)v;
      }
    }
  }
}

extern "C" void kernel_launch(void* const* d_in, const int* in_sizes, int n_in,
                              void* d_out, int out_size, void* d_ws, size_t ws_size,
                              hipStream_t stream) {
  (void)in_sizes; (void)n_in; (void)out_size;
  const float* x  = (const float*)d_in[0];
  const float* wq = (const float*)d_in[1];
  const float* bq = (const float*)d_in[2];
  const float* wk = (const float*)d_in[3];
  const float* bk = (const float*)d_in[4];
  const float* wv = (const float*)d_in[5];
  const float* bv = (const float*)d_in[6];
  const float* wp = (const float*)d_in[7];
  const float* bp = (const float*)d_in[8];
  float* out = (float*)d_out;

  char* ws = (char*)d_ws;
  const size_t MB = 1ull << 20;
  _Float16* qh = (_Float16*)(ws + 0*MB);    // 16 MB; attention output written in place
  _Float16* kh = (_Float16*)(ws + 16*MB);   // 16 MB
  _Float16* vh = (_Float16*)(ws + 32*MB);   // 16 MB, TRANSPOSED layout [b][h][d][t]
  _Float16* xh = (_Float16*)(ws + 48*MB);   // 16 MB (only if ws_size >= 64 MB)

  bool use_xh = ws_size >= 64*MB;
  if (use_xh) {
    cast_x_kernel<<<dim3((M_*C_/4) / 256), 256, 0, stream>>>(x, xh, M_*C_/4);
    gemm_qkv_kernel<0><<<dim3(M_/128, 24), 256, 0, stream>>>(
        xh, nullptr, wq, wk, wv, bq, bk, bv, qh, kh, vh);
  } else {
    gemm_qkv_kernel<1><<<dim3(M_/128, 24), 256, 0, stream>>>(
        nullptr, x, wq, wk, wv, bq, bk, bv, qh, kh, vh);
  }
  attn_kernel<<<dim3(16, NH, B_), 256, 0, stream>>>(qh, kh, vh, qh);
  gemm_proj_kernel<<<dim3(M_/128, C_/128), 256, 0, stream>>>(qh, wp, bp, out);
}

// Round 4
// 252.002 us; speedup vs baseline: 1.9352x; 1.3757x over previous
//
#include <hip/hip_runtime.h>
#include <stdint.h>

typedef __attribute__((ext_vector_type(4))) float f32x4;
typedef __attribute__((ext_vector_type(8))) _Float16 h8;
typedef __attribute__((ext_vector_type(4))) float f4v;
typedef __attribute__((ext_vector_type(4))) _Float16 h4v;

#define B_ 4
#define T_ 2048
#define C_ 1024
#define NH 16
#define HD 64
#define M_ (B_*T_)   // 8192
#define KD 1024      // reduction dim of all GEMMs

#define MFMA16(a, b, c) __builtin_amdgcn_mfma_f32_16x16x32_f16(a, b, c, 0, 0, 0)

// async global->LDS, 16B per lane; LDS dest must be wave-uniform base (HW adds lane*16)
#define GL2LDS16(g, l) \
  __builtin_amdgcn_global_load_lds((const __attribute__((address_space(1))) unsigned int*)(g), \
      (__attribute__((address_space(3))) unsigned int*)(unsigned int)(uintptr_t)(l), 16, 0, 0)

__global__ void cast_x_kernel(const float* __restrict__ src, _Float16* __restrict__ dst, int n4) {
  int i = blockIdx.x * blockDim.x + threadIdx.x;
  if (i < n4) {
    f4v v = ((const f4v*)src)[i];
    ((h4v*)dst)[i] = __builtin_convertvector(v, h4v);
  }
}

// Stage a 128x32 fp32 tile (rows stride KD) into fp16 LDS [128][32], row-major.
__device__ __forceinline__ void stage_f32_128x32(const float* src, _Float16* dst, int lane, int wav) {
  #pragma unroll
  for (int hh = 0; hh < 2; hh++) {
    int row = hh*64 + wav*16 + (lane >> 2);
    int colf = (lane & 3) * 8;
    const float* p = src + (size_t)row * KD + colf;
    f4v a = *(const f4v*)p;
    f4v b = *(const f4v*)(p + 4);
    h8 v;
    v[0]=(_Float16)a[0]; v[1]=(_Float16)a[1]; v[2]=(_Float16)a[2]; v[3]=(_Float16)a[3];
    v[4]=(_Float16)b[0]; v[5]=(_Float16)b[1]; v[6]=(_Float16)b[2]; v[7]=(_Float16)b[3];
    *(h8*)(dst + row*32 + colf) = v;
  }
}

// ---------------- QKV GEMM: Out[M][N] = A[M][K] * W[N][K]^T + bias, 128x128 tile, BK=32 ----------------
// sel==2 (V) is written TRANSPOSED as Vt[b][h][d][t] so attention needs no LDS transpose.
template<int AMODE>
__global__ __launch_bounds__(256) void gemm_qkv_kernel(
    const _Float16* __restrict__ Xh, const float* __restrict__ Xf,
    const float* __restrict__ Wq, const float* __restrict__ Wk, const float* __restrict__ Wv,
    const float* __restrict__ bq, const float* __restrict__ bk, const float* __restrict__ bv,
    _Float16* __restrict__ Qo, _Float16* __restrict__ Ko, _Float16* __restrict__ Vo)
{
  __shared__ _Float16 As[128*32];
  __shared__ _Float16 Bs[128*32];
  int tid = threadIdx.x;
  int lane = tid & 63, wav = tid >> 6;
  int mb = blockIdx.x;
  int nbg = blockIdx.y;
  int sel = nbg >> 3, nb = nbg & 7;
  const float* W = sel == 0 ? Wq : (sel == 1 ? Wk : Wv);
  const float* bias = sel == 0 ? bq : (sel == 1 ? bk : bv);
  _Float16* Out = sel == 0 ? Qo : (sel == 1 ? Ko : Vo);
  int m0 = mb * 128, n0 = nb * 128;

  f32x4 acc[4][4] = {};

  int r_in = lane >> 2;          // 0..15 row within 16-row chunk
  int c8   = (lane & 3) * 8;     // k-element offset 0,8,16,24
  int l15 = lane & 15, l4 = lane >> 4;
  int wr = (wav >> 1) * 64, wc = (wav & 1) * 64;

  for (int k0 = 0; k0 < KD; k0 += 32) {
    if (AMODE == 0) {
      GL2LDS16(Xh + (size_t)(m0 +      wav*16 + r_in)*KD + k0 + c8, As +        wav*512);
      GL2LDS16(Xh + (size_t)(m0 + 64 + wav*16 + r_in)*KD + k0 + c8, As + 2048 + wav*512);
    } else {
      stage_f32_128x32(Xf + (size_t)m0 * KD + k0, As, lane, wav);
    }
    stage_f32_128x32(W + (size_t)n0 * KD + k0, Bs, lane, wav);
    __syncthreads();

    h8 af[4], bf[4];
    #pragma unroll
    for (int f = 0; f < 4; f++) {
      af[f] = *(const h8*)(As + (wr + f*16 + l15)*32 + l4*8);
      bf[f] = *(const h8*)(Bs + (wc + f*16 + l15)*32 + l4*8);
    }
    #pragma unroll
    for (int i = 0; i < 4; i++)
      #pragma unroll
      for (int j = 0; j < 4; j++)
        acc[i][j] = MFMA16(af[i], bf[j], acc[i][j]);
    __syncthreads();
  }

  if (sel == 2) {
    // transposed V epilogue: Vt[((b*NH+h)*HD+d)*T_ + t], 4 consecutive t per reg quad
    #pragma unroll
    for (int i = 0; i < 4; i++) {
      int mrow = m0 + wr + i*16 + l4*4;
      int bb = mrow >> 11, t = mrow & 2047;
      #pragma unroll
      for (int j = 0; j < 4; j++) {
        int ncol = n0 + wc + j*16 + l15;
        float bval = bias[ncol];
        int hh = ncol >> 6, d = ncol & 63;
        h4v v;
        #pragma unroll
        for (int r = 0; r < 4; r++) v[r] = (_Float16)(acc[i][j][r] + bval);
        *(h4v*)(Vo + ((size_t)(bb*NH + hh)*HD + d)*T_ + t) = v;
      }
    }
  } else {
    #pragma unroll
    for (int i = 0; i < 4; i++) {
      int mrow = m0 + wr + i*16 + l4*4;
      #pragma unroll
      for (int j = 0; j < 4; j++) {
        int ncol = n0 + wc + j*16 + l15;
        float bval = bias[ncol];
        #pragma unroll
        for (int r = 0; r < 4; r++)
          Out[(size_t)(mrow + r)*C_ + ncol] = (_Float16)(acc[i][j][r] + bval);
      }
    }
  }
}

// ---------------- Output projection: Out[M][N] = A[M][K](fp16) * W[N][K]^T(fp32) + bias, clamp ±10 ----------------
__global__ __launch_bounds__(256) void gemm_proj_kernel(
    const _Float16* __restrict__ A, const float* __restrict__ W,
    const float* __restrict__ bias, float* __restrict__ Out)
{
  __shared__ _Float16 As[128*32];
  __shared__ _Float16 Bs[128*32];
  int tid = threadIdx.x;
  int lane = tid & 63, wav = tid >> 6;
  int m0 = blockIdx.x * 128, n0 = blockIdx.y * 128;

  f32x4 acc[4][4] = {};
  int r_in = lane >> 2;
  int c8   = (lane & 3) * 8;
  int l15 = lane & 15, l4 = lane >> 4;
  int wr = (wav >> 1) * 64, wc = (wav & 1) * 64;

  for (int k0 = 0; k0 < KD; k0 += 32) {
    GL2LDS16(A + (size_t)(m0 +      wav*16 + r_in)*KD + k0 + c8, As +        wav*512);
    GL2LDS16(A + (size_t)(m0 + 64 + wav*16 + r_in)*KD + k0 + c8, As + 2048 + wav*512);
    stage_f32_128x32(W + (size_t)n0 * KD + k0, Bs, lane, wav);
    __syncthreads();

    h8 af[4], bf[4];
    #pragma unroll
    for (int f = 0; f < 4; f++) {
      af[f] = *(const h8*)(As + (wr + f*16 + l15)*32 + l4*8);
      bf[f] = *(const h8*)(Bs + (wc + f*16 + l15)*32 + l4*8);
    }
    #pragma unroll
    for (int i = 0; i < 4; i++)
      #pragma unroll
      for (int j = 0; j < 4; j++)
        acc[i][j] = MFMA16(af[i], bf[j], acc[i][j]);
    __syncthreads();
  }

  #pragma unroll
  for (int i = 0; i < 4; i++) {
    int mrow = m0 + wr + i*16 + l4*4;
    #pragma unroll
    for (int j = 0; j < 4; j++) {
      int ncol = n0 + wc + j*16 + l15;
      float bval = bias[ncol];
      #pragma unroll
      for (int r = 0; r < 4; r++) {
        float v = acc[i][j][r] + bval;
        v = fminf(10.f, fmaxf(-10.f, v));
        Out[(size_t)(mrow + r)*C_ + ncol] = v;
      }
    }
  }
}

// ---------------- Flash attention, causal, barrier-free. ----------------
// Wave = 32 q rows (two 16-row MFMA groups sharing K/V fragment loads -> 2 independent
// softmax chains, half the K/V traffic per row). Block = 4 waves on tiles
// {i, 31-i, 32+i, 63-i} of one (b,h): constant total work -> uniform blocks.
// Swapped QK^T (S^T = K*Q^T) keeps q lane-local; V pre-transposed in global.
// O overwrites Q in place (each wave's rows x head-slice are exclusively its own).
__global__ __launch_bounds__(256, 4) void attn_kernel(
    const _Float16* Q, const _Float16* __restrict__ K,
    const _Float16* __restrict__ Vt, _Float16* O)
{
  __shared__ _Float16 Plds[4][2*16*40];  // per wave: 2 groups of P[16 q][32 k], row stride 40
  int tid = threadIdx.x;
  int lane = tid & 63, w = tid >> 6;
  int i = blockIdx.x, h = blockIdx.y, b = blockIdx.z;
  int l15 = lane & 15, l4 = lane >> 4;
  _Float16* PlA = &Plds[w][0];
  _Float16* PlB = &Plds[w][640];
  const _Float16* Kbh = K + (size_t)b*T_*C_ + h*HD;
  const _Float16* Vbh = Vt + (size_t)(b*NH + h)*HD*T_;

  // this wave's 32-row tile: {i, 31-i, 32+i, 63-i}[w]
  int t = (w >> 1)*32 + ((w & 1) ? (31 - i) : i);
  int q0 = t * 32;
  int qa = q0 + l15;        // group A q row
  int qb = q0 + 16 + l15;   // group B q row

  const _Float16* qbase0 = Q + (size_t)(b*T_ + qa)*C_ + h*HD;
  const _Float16* qbase1 = Q + (size_t)(b*T_ + qb)*C_ + h*HD;
  h8 qf00 = *(const h8*)(qbase0 + l4*8);
  h8 qf01 = *(const h8*)(qbase0 + 32 + l4*8);
  h8 qf10 = *(const h8*)(qbase1 + l4*8);
  h8 qf11 = *(const h8*)(qbase1 + 32 + l4*8);

  f32x4 accA[4] = {}, accB[4] = {};
  float mA = -INFINITY, lA = 0.f;
  float mB = -INFINITY, lB = 0.f;
  int last = q0;            // q0 is 32-aligned: diagonal step

  h8 kf0 = *(const h8*)(Kbh + (size_t)l15*C_ + l4*8);
  h8 kf1 = *(const h8*)(Kbh + (size_t)l15*C_ + 32 + l4*8);
  h8 kf2 = *(const h8*)(Kbh + (size_t)(16 + l15)*C_ + l4*8);
  h8 kf3 = *(const h8*)(Kbh + (size_t)(16 + l15)*C_ + 32 + l4*8);

  #pragma unroll 1
  for (int kb = 0; kb <= last; kb += 32) {
    // V^T fragments for current keys: independent of S chain, issue first
    h8 vf0 = *(const h8*)(Vbh + (size_t)(l15     )*T_ + kb + l4*8);
    h8 vf1 = *(const h8*)(Vbh + (size_t)(16 + l15)*T_ + kb + l4*8);
    h8 vf2 = *(const h8*)(Vbh + (size_t)(32 + l15)*T_ + kb + l4*8);
    h8 vf3 = *(const h8*)(Vbh + (size_t)(48 + l15)*T_ + kb + l4*8);

    f32x4 s0a = {}, s1a = {}, s0b = {}, s1b = {};
    s0a = MFMA16(kf0, qf00, s0a); s0a = MFMA16(kf1, qf01, s0a);
    s1a = MFMA16(kf2, qf00, s1a); s1a = MFMA16(kf3, qf01, s1a);
    s0b = MFMA16(kf0, qf10, s0b); s0b = MFMA16(kf1, qf11, s0b);
    s1b = MFMA16(kf2, qf10, s1b); s1b = MFMA16(kf3, qf11, s1b);

    if (kb < last) {        // register-prefetch next K tile
      const _Float16* kn = Kbh + (size_t)(kb + 32)*C_;
      kf0 = *(const h8*)(kn + (size_t)l15*C_ + l4*8);
      kf1 = *(const h8*)(kn + (size_t)l15*C_ + 32 + l4*8);
      kf2 = *(const h8*)(kn + (size_t)(16 + l15)*C_ + l4*8);
      kf3 = *(const h8*)(kn + (size_t)(16 + l15)*C_ + 32 + l4*8);
    }

    // ---- softmax, group A (q = qa) ----
    float scA[8], scB[8];
    #pragma unroll
    for (int j = 0; j < 4; j++) { scA[j] = s0a[j]*0.125f; scA[4+j] = s1a[j]*0.125f; }
    #pragma unroll
    for (int j = 0; j < 4; j++) { scB[j] = s0b[j]*0.125f; scB[4+j] = s1b[j]*0.125f; }
    if (kb == last) {
      #pragma unroll
      for (int r = 0; r < 4; r++) {
        if (kb      + l4*4 + r > qa) scA[r]   = -INFINITY;
        if (kb + 16 + l4*4 + r > qa) scA[4+r] = -INFINITY;
        if (kb + 16 + l4*4 + r > qb) scB[4+r] = -INFINITY;  // B's s0 keys always <= qb
      }
    }
    float mxA = scA[0], mxB = scB[0];
    #pragma unroll
    for (int j = 1; j < 8; j++) { mxA = fmaxf(mxA, scA[j]); mxB = fmaxf(mxB, scB[j]); }
    mxA = fmaxf(mxA, __shfl_xor(mxA, 16)); mxB = fmaxf(mxB, __shfl_xor(mxB, 16));
    mxA = fmaxf(mxA, __shfl_xor(mxA, 32)); mxB = fmaxf(mxB, __shfl_xor(mxB, 32));
    float mnA = fmaxf(mA, mxA),        mnB = fmaxf(mB, mxB);
    float alA = __expf(mA - mnA),      alB = __expf(mB - mnB);
    mA = mnA; mB = mnB;
    float lsA = 0.f, lsB = 0.f;
    h4v pw0a, pw1a, pw0b, pw1b;
    #pragma unroll
    for (int j = 0; j < 4; j++) {
      float e;
      e = __expf(scA[j]   - mnA); lsA += e; pw0a[j] = (_Float16)e;
      e = __expf(scA[4+j] - mnA); lsA += e; pw1a[j] = (_Float16)e;
      e = __expf(scB[j]   - mnB); lsB += e; pw0b[j] = (_Float16)e;
      e = __expf(scB[4+j] - mnB); lsB += e; pw1b[j] = (_Float16)e;
    }
    lsA += __shfl_xor(lsA, 16); lsB += __shfl_xor(lsB, 16);
    lsA += __shfl_xor(lsA, 32); lsB += __shfl_xor(lsB, 32);
    lA = lA*alA + lsA; lB = lB*alB + lsB;

    *(h4v*)(PlA + l15*40 +      l4*4) = pw0a;
    *(h4v*)(PlA + l15*40 + 16 + l4*4) = pw1a;
    *(h4v*)(PlB + l15*40 +      l4*4) = pw0b;
    *(h4v*)(PlB + l15*40 + 16 + l4*4) = pw1b;

    float avA[4], avB[4];
    #pragma unroll
    for (int r = 0; r < 4; r++) { avA[r] = __shfl(alA, l4*4 + r); avB[r] = __shfl(alB, l4*4 + r); }
    #pragma unroll
    for (int c2 = 0; c2 < 4; c2++) {
      accA[c2][0] *= avA[0]; accA[c2][1] *= avA[1]; accA[c2][2] *= avA[2]; accA[c2][3] *= avA[3];
      accB[c2][0] *= avB[0]; accB[c2][1] *= avB[1]; accB[c2][2] *= avB[2]; accB[c2][3] *= avB[3];
    }

    h8 paA = *(const h8*)(PlA + l15*40 + l4*8);
    h8 paB = *(const h8*)(PlB + l15*40 + l4*8);
    accA[0] = MFMA16(paA, vf0, accA[0]);
    accA[1] = MFMA16(paA, vf1, accA[1]);
    accA[2] = MFMA16(paA, vf2, accA[2]);
    accA[3] = MFMA16(paA, vf3, accA[3]);
    accB[0] = MFMA16(paB, vf0, accB[0]);
    accB[1] = MFMA16(paB, vf1, accB[1]);
    accB[2] = MFMA16(paB, vf2, accB[2]);
    accB[3] = MFMA16(paB, vf3, accB[3]);
  }

  float lrA[4], lrB[4];
  #pragma unroll
  for (int r = 0; r < 4; r++) { lrA[r] = __shfl(lA, l4*4 + r); lrB[r] = __shfl(lB, l4*4 + r); }
  #pragma unroll
  for (int c2 = 0; c2 < 4; c2++) {
    #pragma unroll
    for (int r = 0; r < 4; r++) {
      float va = accA[c2][r] / lrA[r];
      float vb = accB[c2][r] / lrB[r];
      va = fminf(10.f, fmaxf(-10.f, va));
      vb = fminf(10.f, fmaxf(-10.f, vb));
      O[(size_t)(b*T_ + q0      + l4*4 + r)*C_ + h*HD + c2*16 + l15] = (_Float16)va;
      O[(size_t)(b*T_ + q0 + 16 + l4*4 + r)*C_ + h*HD + c2*16 + l15] = (_Float16)vb;
    }
  }
}

extern "C" void kernel_launch(void* const* d_in, const int* in_sizes, int n_in,
                              void* d_out, int out_size, void* d_ws, size_t ws_size,
                              hipStream_t stream) {
  (void)in_sizes; (void)n_in; (void)out_size;
  const float* x  = (const float*)d_in[0];
  const float* wq = (const float*)d_in[1];
  const float* bq = (const float*)d_in[2];
  const float* wk = (const float*)d_in[3];
  const float* bk = (const float*)d_in[4];
  const float* wv = (const float*)d_in[5];
  const float* bv = (const float*)d_in[6];
  const float* wp = (const float*)d_in[7];
  const float* bp = (const float*)d_in[8];
  float* out = (float*)d_out;

  char* ws = (char*)d_ws;
  const size_t MB = 1ull << 20;
  _Float16* qh = (_Float16*)(ws + 0*MB);    // 16 MB; attention output written in place
  _Float16* kh = (_Float16*)(ws + 16*MB);   // 16 MB
  _Float16* vh = (_Float16*)(ws + 32*MB);   // 16 MB, TRANSPOSED layout [b][h][d][t]
  _Float16* xh = (_Float16*)(ws + 48*MB);   // 16 MB (only if ws_size >= 64 MB)

  bool use_xh = ws_size >= 64*MB;
  if (use_xh) {
    cast_x_kernel<<<dim3((M_*C_/4) / 256), 256, 0, stream>>>(x, xh, M_*C_/4);
    gemm_qkv_kernel<0><<<dim3(M_/128, 24), 256, 0, stream>>>(
        xh, nullptr, wq, wk, wv, bq, bk, bv, qh, kh, vh);
  } else {
    gemm_qkv_kernel<1><<<dim3(M_/128, 24), 256, 0, stream>>>(
        nullptr, x, wq, wk, wv, bq, bk, bv, qh, kh, vh);
  }
  attn_kernel<<<dim3(16, NH, B_), 256, 0, stream>>>(qh, kh, vh, qh);
  gemm_proj_kernel<<<dim3(M_/128, C_/128), 256, 0, stream>>>(qh, wp, bp, out);
}

// Round 5
// 240.645 us; speedup vs baseline: 2.0266x; 1.0472x over previous
//
#include <hip/hip_runtime.h>
#include <stdint.h>

typedef __attribute__((ext_vector_type(4))) float f32x4;
typedef __attribute__((ext_vector_type(8))) _Float16 h8;
typedef __attribute__((ext_vector_type(4))) float f4v;
typedef __attribute__((ext_vector_type(4))) _Float16 h4v;

#define B_ 4
#define T_ 2048
#define C_ 1024
#define NH 16
#define HD 64
#define M_ (B_*T_)   // 8192
#define KD 1024      // reduction dim of all GEMMs

#define MFMA16(a, b, c) __builtin_amdgcn_mfma_f32_16x16x32_f16(a, b, c, 0, 0, 0)

// async global->LDS, 16B per lane; LDS dest must be wave-uniform base (HW adds lane*16)
#define GL2LDS16(g, l) \
  __builtin_amdgcn_global_load_lds((const __attribute__((address_space(1))) unsigned int*)(g), \
      (__attribute__((address_space(3))) unsigned int*)(unsigned int)(uintptr_t)(l), 16, 0, 0)

__global__ void cast_x_kernel(const float* __restrict__ src, _Float16* __restrict__ dst, int n4) {
  int i = blockIdx.x * blockDim.x + threadIdx.x;
  if (i < n4) {
    f4v v = ((const f4v*)src)[i];
    ((h4v*)dst)[i] = __builtin_convertvector(v, h4v);
  }
}

// Stage a 128x32 fp32 tile (rows stride KD) into fp16 LDS [128][32], row-major.
__device__ __forceinline__ void stage_f32_128x32(const float* src, _Float16* dst, int lane, int wav) {
  #pragma unroll
  for (int hh = 0; hh < 2; hh++) {
    int row = hh*64 + wav*16 + (lane >> 2);
    int colf = (lane & 3) * 8;
    const float* p = src + (size_t)row * KD + colf;
    f4v a = *(const f4v*)p;
    f4v b = *(const f4v*)(p + 4);
    h8 v;
    v[0]=(_Float16)a[0]; v[1]=(_Float16)a[1]; v[2]=(_Float16)a[2]; v[3]=(_Float16)a[3];
    v[4]=(_Float16)b[0]; v[5]=(_Float16)b[1]; v[6]=(_Float16)b[2]; v[7]=(_Float16)b[3];
    *(h8*)(dst + row*32 + colf) = v;
  }
}

// ---------------- QKV GEMM: Out[M][N] = A[M][K] * W[N][K]^T + bias, 128x128 tile, BK=32 ----------------
// sel==2 (V) is written TRANSPOSED as Vt[b][h][d][t] so attention needs no LDS transpose.
template<int AMODE>
__global__ __launch_bounds__(256) void gemm_qkv_kernel(
    const _Float16* __restrict__ Xh, const float* __restrict__ Xf,
    const float* __restrict__ Wq, const float* __restrict__ Wk, const float* __restrict__ Wv,
    const float* __restrict__ bq, const float* __restrict__ bk, const float* __restrict__ bv,
    _Float16* __restrict__ Qo, _Float16* __restrict__ Ko, _Float16* __restrict__ Vo)
{
  __shared__ _Float16 As[128*32];
  __shared__ _Float16 Bs[128*32];
  int tid = threadIdx.x;
  int lane = tid & 63, wav = tid >> 6;
  int mb = blockIdx.x;
  int nbg = blockIdx.y;
  int sel = nbg >> 3, nb = nbg & 7;
  const float* W = sel == 0 ? Wq : (sel == 1 ? Wk : Wv);
  const float* bias = sel == 0 ? bq : (sel == 1 ? bk : bv);
  _Float16* Out = sel == 0 ? Qo : (sel == 1 ? Ko : Vo);
  int m0 = mb * 128, n0 = nb * 128;

  f32x4 acc[4][4] = {};

  int r_in = lane >> 2;          // 0..15 row within 16-row chunk
  int c8   = (lane & 3) * 8;     // k-element offset 0,8,16,24
  int l15 = lane & 15, l4 = lane >> 4;
  int wr = (wav >> 1) * 64, wc = (wav & 1) * 64;

  for (int k0 = 0; k0 < KD; k0 += 32) {
    if (AMODE == 0) {
      GL2LDS16(Xh + (size_t)(m0 +      wav*16 + r_in)*KD + k0 + c8, As +        wav*512);
      GL2LDS16(Xh + (size_t)(m0 + 64 + wav*16 + r_in)*KD + k0 + c8, As + 2048 + wav*512);
    } else {
      stage_f32_128x32(Xf + (size_t)m0 * KD + k0, As, lane, wav);
    }
    stage_f32_128x32(W + (size_t)n0 * KD + k0, Bs, lane, wav);
    __syncthreads();

    h8 af[4], bf[4];
    #pragma unroll
    for (int f = 0; f < 4; f++) {
      af[f] = *(const h8*)(As + (wr + f*16 + l15)*32 + l4*8);
      bf[f] = *(const h8*)(Bs + (wc + f*16 + l15)*32 + l4*8);
    }
    #pragma unroll
    for (int i = 0; i < 4; i++)
      #pragma unroll
      for (int j = 0; j < 4; j++)
        acc[i][j] = MFMA16(af[i], bf[j], acc[i][j]);
    __syncthreads();
  }

  if (sel == 2) {
    // transposed V epilogue: Vt[((b*NH+h)*HD+d)*T_ + t], 4 consecutive t per reg quad
    #pragma unroll
    for (int i = 0; i < 4; i++) {
      int mrow = m0 + wr + i*16 + l4*4;
      int bb = mrow >> 11, t = mrow & 2047;
      #pragma unroll
      for (int j = 0; j < 4; j++) {
        int ncol = n0 + wc + j*16 + l15;
        float bval = bias[ncol];
        int hh = ncol >> 6, d = ncol & 63;
        h4v v;
        #pragma unroll
        for (int r = 0; r < 4; r++) v[r] = (_Float16)(acc[i][j][r] + bval);
        *(h4v*)(Vo + ((size_t)(bb*NH + hh)*HD + d)*T_ + t) = v;
      }
    }
  } else {
    #pragma unroll
    for (int i = 0; i < 4; i++) {
      int mrow = m0 + wr + i*16 + l4*4;
      #pragma unroll
      for (int j = 0; j < 4; j++) {
        int ncol = n0 + wc + j*16 + l15;
        float bval = bias[ncol];
        #pragma unroll
        for (int r = 0; r < 4; r++)
          Out[(size_t)(mrow + r)*C_ + ncol] = (_Float16)(acc[i][j][r] + bval);
      }
    }
  }
}

// ---------------- Output projection: Out[M][N] = A[M][K](fp16) * W[N][K]^T(fp32) + bias, clamp ±10 ----------------
__global__ __launch_bounds__(256) void gemm_proj_kernel(
    const _Float16* __restrict__ A, const float* __restrict__ W,
    const float* __restrict__ bias, float* __restrict__ Out)
{
  __shared__ _Float16 As[128*32];
  __shared__ _Float16 Bs[128*32];
  int tid = threadIdx.x;
  int lane = tid & 63, wav = tid >> 6;
  int m0 = blockIdx.x * 128, n0 = blockIdx.y * 128;

  f32x4 acc[4][4] = {};
  int r_in = lane >> 2;
  int c8   = (lane & 3) * 8;
  int l15 = lane & 15, l4 = lane >> 4;
  int wr = (wav >> 1) * 64, wc = (wav & 1) * 64;

  for (int k0 = 0; k0 < KD; k0 += 32) {
    GL2LDS16(A + (size_t)(m0 +      wav*16 + r_in)*KD + k0 + c8, As +        wav*512);
    GL2LDS16(A + (size_t)(m0 + 64 + wav*16 + r_in)*KD + k0 + c8, As + 2048 + wav*512);
    stage_f32_128x32(W + (size_t)n0 * KD + k0, Bs, lane, wav);
    __syncthreads();

    h8 af[4], bf[4];
    #pragma unroll
    for (int f = 0; f < 4; f++) {
      af[f] = *(const h8*)(As + (wr + f*16 + l15)*32 + l4*8);
      bf[f] = *(const h8*)(Bs + (wc + f*16 + l15)*32 + l4*8);
    }
    #pragma unroll
    for (int i = 0; i < 4; i++)
      #pragma unroll
      for (int j = 0; j < 4; j++)
        acc[i][j] = MFMA16(af[i], bf[j], acc[i][j]);
    __syncthreads();
  }

  #pragma unroll
  for (int i = 0; i < 4; i++) {
    int mrow = m0 + wr + i*16 + l4*4;
    #pragma unroll
    for (int j = 0; j < 4; j++) {
      int ncol = n0 + wc + j*16 + l15;
      float bval = bias[ncol];
      #pragma unroll
      for (int r = 0; r < 4; r++) {
        float v = acc[i][j][r] + bval;
        v = fminf(10.f, fmaxf(-10.f, v));
        Out[(size_t)(mrow + r)*C_ + ncol] = v;
      }
    }
  }
}

// ---------------- Flash attention, causal, barrier-free, 1 wave per block. ----------------
// Block = 64 threads = one wave handling 32 q rows (two 16-row MFMA groups sharing K/V
// fragment loads -> 2 independent softmax chains). 4096 independent blocks; longest tile
// dispatched first (tile = 63 - p/64) so the scheduler backfills the tail with short tiles.
// Swapped QK^T (S^T = K*Q^T) keeps q lane-local; V pre-transposed in global.
// O overwrites Q in place (each block's rows x head-slice are exclusively its own).
__global__ __launch_bounds__(64) void attn_kernel(
    const _Float16* Q, const _Float16* __restrict__ K,
    const _Float16* __restrict__ Vt, _Float16* O)
{
  __shared__ _Float16 Plds[2*16*40];  // 2 groups of P[16 q][32 k], row stride 40
  int lane = threadIdx.x & 63;
  int p = blockIdx.x;
  int t  = 63 - (p >> 6);            // tile (longest first)
  int bh = p & 63;
  int b = bh >> 4, h = bh & 15;
  int l15 = lane & 15, l4 = lane >> 4;
  _Float16* PlA = &Plds[0];
  _Float16* PlB = &Plds[640];
  const _Float16* Kbh = K + (size_t)b*T_*C_ + h*HD;
  const _Float16* Vbh = Vt + (size_t)(b*NH + h)*HD*T_;

  int q0 = t * 32;
  int qa = q0 + l15;        // group A q row
  int qb = q0 + 16 + l15;   // group B q row

  const _Float16* qbase0 = Q + (size_t)(b*T_ + qa)*C_ + h*HD;
  const _Float16* qbase1 = Q + (size_t)(b*T_ + qb)*C_ + h*HD;
  h8 qf00 = *(const h8*)(qbase0 + l4*8);
  h8 qf01 = *(const h8*)(qbase0 + 32 + l4*8);
  h8 qf10 = *(const h8*)(qbase1 + l4*8);
  h8 qf11 = *(const h8*)(qbase1 + 32 + l4*8);

  f32x4 accA[4] = {}, accB[4] = {};
  float mA = -INFINITY, lA = 0.f;
  float mB = -INFINITY, lB = 0.f;
  int last = q0;            // q0 is 32-aligned: diagonal step

  h8 kf0 = *(const h8*)(Kbh + (size_t)l15*C_ + l4*8);
  h8 kf1 = *(const h8*)(Kbh + (size_t)l15*C_ + 32 + l4*8);
  h8 kf2 = *(const h8*)(Kbh + (size_t)(16 + l15)*C_ + l4*8);
  h8 kf3 = *(const h8*)(Kbh + (size_t)(16 + l15)*C_ + 32 + l4*8);

  #pragma unroll 1
  for (int kb = 0; kb <= last; kb += 32) {
    // V^T fragments for current keys: independent of S chain, issue first
    h8 vf0 = *(const h8*)(Vbh + (size_t)(l15     )*T_ + kb + l4*8);
    h8 vf1 = *(const h8*)(Vbh + (size_t)(16 + l15)*T_ + kb + l4*8);
    h8 vf2 = *(const h8*)(Vbh + (size_t)(32 + l15)*T_ + kb + l4*8);
    h8 vf3 = *(const h8*)(Vbh + (size_t)(48 + l15)*T_ + kb + l4*8);

    f32x4 s0a = {}, s1a = {}, s0b = {}, s1b = {};
    s0a = MFMA16(kf0, qf00, s0a); s0a = MFMA16(kf1, qf01, s0a);
    s1a = MFMA16(kf2, qf00, s1a); s1a = MFMA16(kf3, qf01, s1a);
    s0b = MFMA16(kf0, qf10, s0b); s0b = MFMA16(kf1, qf11, s0b);
    s1b = MFMA16(kf2, qf10, s1b); s1b = MFMA16(kf3, qf11, s1b);

    if (kb < last) {        // register-prefetch next K tile
      const _Float16* kn = Kbh + (size_t)(kb + 32)*C_;
      kf0 = *(const h8*)(kn + (size_t)l15*C_ + l4*8);
      kf1 = *(const h8*)(kn + (size_t)l15*C_ + 32 + l4*8);
      kf2 = *(const h8*)(kn + (size_t)(16 + l15)*C_ + l4*8);
      kf3 = *(const h8*)(kn + (size_t)(16 + l15)*C_ + 32 + l4*8);
    }

    float scA[8], scB[8];
    #pragma unroll
    for (int j = 0; j < 4; j++) { scA[j] = s0a[j]*0.125f; scA[4+j] = s1a[j]*0.125f; }
    #pragma unroll
    for (int j = 0; j < 4; j++) { scB[j] = s0b[j]*0.125f; scB[4+j] = s1b[j]*0.125f; }
    if (kb == last) {
      #pragma unroll
      for (int r = 0; r < 4; r++) {
        if (kb      + l4*4 + r > qa) scA[r]   = -INFINITY;
        if (kb + 16 + l4*4 + r > qa) scA[4+r] = -INFINITY;
        if (kb + 16 + l4*4 + r > qb) scB[4+r] = -INFINITY;  // B's s0 keys always <= qb
      }
    }
    float mxA = scA[0], mxB = scB[0];
    #pragma unroll
    for (int j = 1; j < 8; j++) { mxA = fmaxf(mxA, scA[j]); mxB = fmaxf(mxB, scB[j]); }
    mxA = fmaxf(mxA, __shfl_xor(mxA, 16)); mxB = fmaxf(mxB, __shfl_xor(mxB, 16));
    mxA = fmaxf(mxA, __shfl_xor(mxA, 32)); mxB = fmaxf(mxB, __shfl_xor(mxB, 32));
    float mnA = fmaxf(mA, mxA),        mnB = fmaxf(mB, mxB);
    float alA = __expf(mA - mnA),      alB = __expf(mB - mnB);
    mA = mnA; mB = mnB;
    float lsA = 0.f, lsB = 0.f;
    h4v pw0a, pw1a, pw0b, pw1b;
    #pragma unroll
    for (int j = 0; j < 4; j++) {
      float e;
      e = __expf(scA[j]   - mnA); lsA += e; pw0a[j] = (_Float16)e;
      e = __expf(scA[4+j] - mnA); lsA += e; pw1a[j] = (_Float16)e;
      e = __expf(scB[j]   - mnB); lsB += e; pw0b[j] = (_Float16)e;
      e = __expf(scB[4+j] - mnB); lsB += e; pw1b[j] = (_Float16)e;
    }
    lsA += __shfl_xor(lsA, 16); lsB += __shfl_xor(lsB, 16);
    lsA += __shfl_xor(lsA, 32); lsB += __shfl_xor(lsB, 32);
    lA = lA*alA + lsA; lB = lB*alB + lsB;

    *(h4v*)(PlA + l15*40 +      l4*4) = pw0a;
    *(h4v*)(PlA + l15*40 + 16 + l4*4) = pw1a;
    *(h4v*)(PlB + l15*40 +      l4*4) = pw0b;
    *(h4v*)(PlB + l15*40 + 16 + l4*4) = pw1b;

    float avA[4], avB[4];
    #pragma unroll
    for (int r = 0; r < 4; r++) { avA[r] = __shfl(alA, l4*4 + r); avB[r] = __shfl(alB, l4*4 + r); }
    #pragma unroll
    for (int c2 = 0; c2 < 4; c2++) {
      accA[c2][0] *= avA[0]; accA[c2][1] *= avA[1]; accA[c2][2] *= avA[2]; accA[c2][3] *= avA[3];
      accB[c2][0] *= avB[0]; accB[c2][1] *= avB[1]; accB[c2][2] *= avB[2]; accB[c2][3] *= avB[3];
    }

    h8 paA = *(const h8*)(PlA + l15*40 + l4*8);
    h8 paB = *(const h8*)(PlB + l15*40 + l4*8);
    accA[0] = MFMA16(paA, vf0, accA[0]);
    accA[1] = MFMA16(paA, vf1, accA[1]);
    accA[2] = MFMA16(paA, vf2, accA[2]);
    accA[3] = MFMA16(paA, vf3, accA[3]);
    accB[0] = MFMA16(paB, vf0, accB[0]);
    accB[1] = MFMA16(paB, vf1, accB[1]);
    accB[2] = MFMA16(paB, vf2, accB[2]);
    accB[3] = MFMA16(paB, vf3, accB[3]);
  }

  float lrA[4], lrB[4];
  #pragma unroll
  for (int r = 0; r < 4; r++) { lrA[r] = __shfl(lA, l4*4 + r); lrB[r] = __shfl(lB, l4*4 + r); }
  #pragma unroll
  for (int c2 = 0; c2 < 4; c2++) {
    #pragma unroll
    for (int r = 0; r < 4; r++) {
      float va = accA[c2][r] / lrA[r];
      float vb = accB[c2][r] / lrB[r];
      va = fminf(10.f, fmaxf(-10.f, va));
      vb = fminf(10.f, fmaxf(-10.f, vb));
      O[(size_t)(b*T_ + q0      + l4*4 + r)*C_ + h*HD + c2*16 + l15] = (_Float16)va;
      O[(size_t)(b*T_ + q0 + 16 + l4*4 + r)*C_ + h*HD + c2*16 + l15] = (_Float16)vb;
    }
  }
}

extern "C" void kernel_launch(void* const* d_in, const int* in_sizes, int n_in,
                              void* d_out, int out_size, void* d_ws, size_t ws_size,
                              hipStream_t stream) {
  (void)in_sizes; (void)n_in; (void)out_size;
  const float* x  = (const float*)d_in[0];
  const float* wq = (const float*)d_in[1];
  const float* bq = (const float*)d_in[2];
  const float* wk = (const float*)d_in[3];
  const float* bk = (const float*)d_in[4];
  const float* wv = (const float*)d_in[5];
  const float* bv = (const float*)d_in[6];
  const float* wp = (const float*)d_in[7];
  const float* bp = (const float*)d_in[8];
  float* out = (float*)d_out;

  char* ws = (char*)d_ws;
  const size_t MB = 1ull << 20;
  _Float16* qh = (_Float16*)(ws + 0*MB);    // 16 MB; attention output written in place
  _Float16* kh = (_Float16*)(ws + 16*MB);   // 16 MB
  _Float16* vh = (_Float16*)(ws + 32*MB);   // 16 MB, TRANSPOSED layout [b][h][d][t]
  _Float16* xh = (_Float16*)(ws + 48*MB);   // 16 MB (only if ws_size >= 64 MB)

  bool use_xh = ws_size >= 64*MB;
  if (use_xh) {
    cast_x_kernel<<<dim3((M_*C_/4) / 256), 256, 0, stream>>>(x, xh, M_*C_/4);
    gemm_qkv_kernel<0><<<dim3(M_/128, 24), 256, 0, stream>>>(
        xh, nullptr, wq, wk, wv, bq, bk, bv, qh, kh, vh);
  } else {
    gemm_qkv_kernel<1><<<dim3(M_/128, 24), 256, 0, stream>>>(
        nullptr, x, wq, wk, wv, bq, bk, bv, qh, kh, vh);
  }
  attn_kernel<<<dim3(64*64), 64, 0, stream>>>(qh, kh, vh, qh);
  gemm_proj_kernel<<<dim3(M_/128, C_/128), 256, 0, stream>>>(qh, wp, bp, out);
}

// Round 6
// 238.959 us; speedup vs baseline: 2.0409x; 1.0071x over previous
//
#include <hip/hip_runtime.h>
#include <stdint.h>

typedef __attribute__((ext_vector_type(4))) float f32x4;
typedef __attribute__((ext_vector_type(8))) _Float16 h8;
typedef __attribute__((ext_vector_type(4))) float f4v;
typedef __attribute__((ext_vector_type(4))) _Float16 h4v;

#define B_ 4
#define T_ 2048
#define C_ 1024
#define NH 16
#define HD 64
#define M_ (B_*T_)   // 8192
#define KD 1024      // reduction dim of all GEMMs

#define MFMA16(a, b, c) __builtin_amdgcn_mfma_f32_16x16x32_f16(a, b, c, 0, 0, 0)

#if __has_builtin(__builtin_amdgcn_exp2f)
#define EXP2(x) __builtin_amdgcn_exp2f(x)
#else
#define EXP2(x) exp2f(x)
#endif

#if __has_builtin(__builtin_amdgcn_cvt_pkrtz)
static __device__ __forceinline__ unsigned pk16(float a, float b) {
  return __builtin_bit_cast(unsigned, __builtin_amdgcn_cvt_pkrtz(a, b));
}
#else
static __device__ __forceinline__ unsigned pk16(float a, float b) {
  union { _Float16 h[2]; unsigned u; } x;
  x.h[0] = (_Float16)a; x.h[1] = (_Float16)b; return x.u;
}
#endif

// async global->LDS, 16B per lane; LDS dest must be wave-uniform base (HW adds lane*16)
#define GL2LDS16(g, l) \
  __builtin_amdgcn_global_load_lds((const __attribute__((address_space(1))) unsigned int*)(g), \
      (__attribute__((address_space(3))) unsigned int*)(unsigned int)(uintptr_t)(l), 16, 0, 0)

__global__ void cast_x_kernel(const float* __restrict__ src, _Float16* __restrict__ dst, int n4) {
  int i = blockIdx.x * blockDim.x + threadIdx.x;
  if (i < n4) {
    f4v v = ((const f4v*)src)[i];
    ((h4v*)dst)[i] = __builtin_convertvector(v, h4v);
  }
}

// Stage a 128x32 fp32 tile (rows stride KD) into fp16 LDS [128][32], row-major.
__device__ __forceinline__ void stage_f32_128x32(const float* src, _Float16* dst, int lane, int wav) {
  #pragma unroll
  for (int hh = 0; hh < 2; hh++) {
    int row = hh*64 + wav*16 + (lane >> 2);
    int colf = (lane & 3) * 8;
    const float* p = src + (size_t)row * KD + colf;
    f4v a = *(const f4v*)p;
    f4v b = *(const f4v*)(p + 4);
    h8 v;
    v[0]=(_Float16)a[0]; v[1]=(_Float16)a[1]; v[2]=(_Float16)a[2]; v[3]=(_Float16)a[3];
    v[4]=(_Float16)b[0]; v[5]=(_Float16)b[1]; v[6]=(_Float16)b[2]; v[7]=(_Float16)b[3];
    *(h8*)(dst + row*32 + colf) = v;
  }
}

// ---------------- QKV GEMM: Out[M][N] = A[M][K] * W[N][K]^T + bias, 128x128 tile, BK=32 ----------------
// sel==2 (V) is written TRANSPOSED as Vt[b][h][d][t] so attention needs no LDS transpose.
template<int AMODE>
__global__ __launch_bounds__(256) void gemm_qkv_kernel(
    const _Float16* __restrict__ Xh, const float* __restrict__ Xf,
    const float* __restrict__ Wq, const float* __restrict__ Wk, const float* __restrict__ Wv,
    const float* __restrict__ bq, const float* __restrict__ bk, const float* __restrict__ bv,
    _Float16* __restrict__ Qo, _Float16* __restrict__ Ko, _Float16* __restrict__ Vo)
{
  __shared__ _Float16 As[128*32];
  __shared__ _Float16 Bs[128*32];
  int tid = threadIdx.x;
  int lane = tid & 63, wav = tid >> 6;
  int mb = blockIdx.x;
  int nbg = blockIdx.y;
  int sel = nbg >> 3, nb = nbg & 7;
  const float* W = sel == 0 ? Wq : (sel == 1 ? Wk : Wv);
  const float* bias = sel == 0 ? bq : (sel == 1 ? bk : bv);
  _Float16* Out = sel == 0 ? Qo : (sel == 1 ? Ko : Vo);
  int m0 = mb * 128, n0 = nb * 128;

  f32x4 acc[4][4] = {};

  int r_in = lane >> 2;          // 0..15 row within 16-row chunk
  int c8   = (lane & 3) * 8;     // k-element offset 0,8,16,24
  int l15 = lane & 15, l4 = lane >> 4;
  int wr = (wav >> 1) * 64, wc = (wav & 1) * 64;

  for (int k0 = 0; k0 < KD; k0 += 32) {
    if (AMODE == 0) {
      GL2LDS16(Xh + (size_t)(m0 +      wav*16 + r_in)*KD + k0 + c8, As +        wav*512);
      GL2LDS16(Xh + (size_t)(m0 + 64 + wav*16 + r_in)*KD + k0 + c8, As + 2048 + wav*512);
    } else {
      stage_f32_128x32(Xf + (size_t)m0 * KD + k0, As, lane, wav);
    }
    stage_f32_128x32(W + (size_t)n0 * KD + k0, Bs, lane, wav);
    __syncthreads();

    h8 af[4], bf[4];
    #pragma unroll
    for (int f = 0; f < 4; f++) {
      af[f] = *(const h8*)(As + (wr + f*16 + l15)*32 + l4*8);
      bf[f] = *(const h8*)(Bs + (wc + f*16 + l15)*32 + l4*8);
    }
    #pragma unroll
    for (int i = 0; i < 4; i++)
      #pragma unroll
      for (int j = 0; j < 4; j++)
        acc[i][j] = MFMA16(af[i], bf[j], acc[i][j]);
    __syncthreads();
  }

  if (sel == 2) {
    // transposed V epilogue: Vt[((b*NH+h)*HD+d)*T_ + t], 4 consecutive t per reg quad
    #pragma unroll
    for (int i = 0; i < 4; i++) {
      int mrow = m0 + wr + i*16 + l4*4;
      int bb = mrow >> 11, t = mrow & 2047;
      #pragma unroll
      for (int j = 0; j < 4; j++) {
        int ncol = n0 + wc + j*16 + l15;
        float bval = bias[ncol];
        int hh = ncol >> 6, d = ncol & 63;
        h4v v;
        #pragma unroll
        for (int r = 0; r < 4; r++) v[r] = (_Float16)(acc[i][j][r] + bval);
        *(h4v*)(Vo + ((size_t)(bb*NH + hh)*HD + d)*T_ + t) = v;
      }
    }
  } else {
    #pragma unroll
    for (int i = 0; i < 4; i++) {
      int mrow = m0 + wr + i*16 + l4*4;
      #pragma unroll
      for (int j = 0; j < 4; j++) {
        int ncol = n0 + wc + j*16 + l15;
        float bval = bias[ncol];
        #pragma unroll
        for (int r = 0; r < 4; r++)
          Out[(size_t)(mrow + r)*C_ + ncol] = (_Float16)(acc[i][j][r] + bval);
      }
    }
  }
}

// ---------------- Output projection: Out[M][N] = A[M][K](fp16) * W[N][K]^T(fp32) + bias, clamp ±10 ----------------
__global__ __launch_bounds__(256) void gemm_proj_kernel(
    const _Float16* __restrict__ A, const float* __restrict__ W,
    const float* __restrict__ bias, float* __restrict__ Out)
{
  __shared__ _Float16 As[128*32];
  __shared__ _Float16 Bs[128*32];
  int tid = threadIdx.x;
  int lane = tid & 63, wav = tid >> 6;
  int m0 = blockIdx.x * 128, n0 = blockIdx.y * 128;

  f32x4 acc[4][4] = {};
  int r_in = lane >> 2;
  int c8   = (lane & 3) * 8;
  int l15 = lane & 15, l4 = lane >> 4;
  int wr = (wav >> 1) * 64, wc = (wav & 1) * 64;

  for (int k0 = 0; k0 < KD; k0 += 32) {
    GL2LDS16(A + (size_t)(m0 +      wav*16 + r_in)*KD + k0 + c8, As +        wav*512);
    GL2LDS16(A + (size_t)(m0 + 64 + wav*16 + r_in)*KD + k0 + c8, As + 2048 + wav*512);
    stage_f32_128x32(W + (size_t)n0 * KD + k0, Bs, lane, wav);
    __syncthreads();

    h8 af[4], bf[4];
    #pragma unroll
    for (int f = 0; f < 4; f++) {
      af[f] = *(const h8*)(As + (wr + f*16 + l15)*32 + l4*8);
      bf[f] = *(const h8*)(Bs + (wc + f*16 + l15)*32 + l4*8);
    }
    #pragma unroll
    for (int i = 0; i < 4; i++)
      #pragma unroll
      for (int j = 0; j < 4; j++)
        acc[i][j] = MFMA16(af[i], bf[j], acc[i][j]);
    __syncthreads();
  }

  #pragma unroll
  for (int i = 0; i < 4; i++) {
    int mrow = m0 + wr + i*16 + l4*4;
    #pragma unroll
    for (int j = 0; j < 4; j++) {
      int ncol = n0 + wc + j*16 + l15;
      float bval = bias[ncol];
      #pragma unroll
      for (int r = 0; r < 4; r++) {
        float v = acc[i][j][r] + bval;
        v = fminf(10.f, fmaxf(-10.f, v));
        Out[(size_t)(mrow + r)*C_ + ncol] = v;
      }
    }
  }
}

// ---------------- Flash attention, causal, barrier-free, 1 wave per block, KVBLK=64. ----------------
// Block = 64 threads = one wave; wave processes the tile PAIR (t, 63-t) -> every block
// runs exactly 33 64-key iterations (perfectly uniform grid of 2048 blocks).
// Two 16-row chains per wave share K/V fragments. Swapped QK^T (S^T = K*Q^T) keeps q lane-local.
// Q pre-scaled by (1/8)*log2(e): softmax exponentials are raw v_exp_f32 (2^x), no per-element muls.
// Defer-max (THR=8 in log2 units): rescale of O-accumulator is rare -> P bounded by 2^8.
// V pre-transposed in global (Vt[b][h][d][t]). O overwrites Q in place (rows owned exclusively).
__global__ __launch_bounds__(64) void attn_kernel(
    const _Float16* Q, const _Float16* __restrict__ K,
    const _Float16* __restrict__ Vt, _Float16* O)
{
  __shared__ _Float16 Plds[2][16*72];   // P[16 q][64 k], row stride 72 halves
  int lane = threadIdx.x & 63;
  int p = blockIdx.x;                   // 2048 blocks
  int pair = p >> 6;                    // 0..31
  int bh = p & 63;
  int b = bh >> 4, h = bh & 15;
  int l15 = lane & 15, l4 = lane >> 4;
  _Float16* PlA = &Plds[0][0];
  _Float16* PlB = &Plds[1][0];
  const _Float16* Kbh = K + (size_t)b*T_*C_ + h*HD;
  const _Float16* Vbh = Vt + (size_t)(b*NH + h)*HD*T_;
  const _Float16 QSC = (_Float16)0.18033688011f;   // (1/8)*log2(e)

#define CHAIN(sv, qrow, m, lp, acc, Pl)                                        \
  {                                                                            \
    float sc[16];                                                              \
    _Pragma("unroll") for (int g = 0; g < 4; g++) {                            \
      sc[g*4+0] = sv[g][0]; sc[g*4+1] = sv[g][1];                              \
      sc[g*4+2] = sv[g][2]; sc[g*4+3] = sv[g][3];                              \
    }                                                                          \
    if (kb == lastb) {                                                         \
      _Pragma("unroll") for (int g = 0; g < 4; g++)                            \
        _Pragma("unroll") for (int r = 0; r < 4; r++)                          \
          if (kb + g*16 + l4*4 + r > (qrow)) sc[g*4+r] = -INFINITY;            \
    }                                                                          \
    float mx = sc[0];                                                          \
    _Pragma("unroll") for (int j = 1; j < 16; j++) mx = fmaxf(mx, sc[j]);      \
    mx = fmaxf(mx, __shfl_xor(mx, 16));                                        \
    mx = fmaxf(mx, __shfl_xor(mx, 32));                                        \
    if (__any(mx > (m) + 8.f)) {                                               \
      float mn = fmaxf((m), mx);                                               \
      float al = EXP2((m) - mn);                                               \
      (lp) *= al;                                                              \
      float av0 = __shfl(al, l4*4+0), av1 = __shfl(al, l4*4+1);                \
      float av2 = __shfl(al, l4*4+2), av3 = __shfl(al, l4*4+3);                \
      _Pragma("unroll") for (int c2 = 0; c2 < 4; c2++) {                       \
        acc[c2][0] *= av0; acc[c2][1] *= av1;                                  \
        acc[c2][2] *= av2; acc[c2][3] *= av3;                                  \
      }                                                                        \
      (m) = mn;                                                                \
    }                                                                          \
    _Pragma("unroll") for (int g = 0; g < 4; g++) {                            \
      float e0 = EXP2(sc[g*4+0] - (m)), e1 = EXP2(sc[g*4+1] - (m));            \
      float e2 = EXP2(sc[g*4+2] - (m)), e3 = EXP2(sc[g*4+3] - (m));            \
      (lp) += (e0 + e1) + (e2 + e3);                                           \
      uint2 u; u.x = pk16(e0, e1); u.y = pk16(e2, e3);                         \
      *(uint2*)((Pl) + l15*72 + g*16 + l4*4) = u;                              \
    }                                                                          \
  }

  #pragma unroll 1
  for (int ti = 0; ti < 2; ti++) {
    int t = ti ? (63 - pair) : pair;
    int q0 = t * 32;
    int qa = q0 + l15, qb = q0 + 16 + l15;

    const _Float16* qp0 = Q + (size_t)(b*T_ + qa)*C_ + h*HD;
    const _Float16* qp1 = Q + (size_t)(b*T_ + qb)*C_ + h*HD;
    h8 qf00 = *(const h8*)(qp0 + l4*8)      * QSC;
    h8 qf01 = *(const h8*)(qp0 + 32 + l4*8) * QSC;
    h8 qf10 = *(const h8*)(qp1 + l4*8)      * QSC;
    h8 qf11 = *(const h8*)(qp1 + 32 + l4*8) * QSC;

    f32x4 accA[4] = {}, accB[4] = {};
    float mA = -INFINITY, lAp = 0.f;
    float mB = -INFINITY, lBp = 0.f;
    int lastb = (q0 >> 6) << 6;      // final 64-key block start

    h8 kf0, kf1, kf2, kf3, kf4, kf5, kf6, kf7;
    kf0 = *(const h8*)(Kbh + (size_t)(     l15)*C_ + l4*8);
    kf1 = *(const h8*)(Kbh + (size_t)(     l15)*C_ + 32 + l4*8);
    kf2 = *(const h8*)(Kbh + (size_t)(16 + l15)*C_ + l4*8);
    kf3 = *(const h8*)(Kbh + (size_t)(16 + l15)*C_ + 32 + l4*8);
    kf4 = *(const h8*)(Kbh + (size_t)(32 + l15)*C_ + l4*8);
    kf5 = *(const h8*)(Kbh + (size_t)(32 + l15)*C_ + 32 + l4*8);
    kf6 = *(const h8*)(Kbh + (size_t)(48 + l15)*C_ + l4*8);
    kf7 = *(const h8*)(Kbh + (size_t)(48 + l15)*C_ + 32 + l4*8);

    #pragma unroll 1
    for (int kb = 0; kb <= lastb; kb += 64) {
      // V^T fragments (consumed at iteration end -> latency hidden under softmax)
      h8 vf00 = *(const h8*)(Vbh + (size_t)(     l15)*T_ + kb + l4*8);
      h8 vf01 = *(const h8*)(Vbh + (size_t)(     l15)*T_ + kb + 32 + l4*8);
      h8 vf10 = *(const h8*)(Vbh + (size_t)(16 + l15)*T_ + kb + l4*8);
      h8 vf11 = *(const h8*)(Vbh + (size_t)(16 + l15)*T_ + kb + 32 + l4*8);
      h8 vf20 = *(const h8*)(Vbh + (size_t)(32 + l15)*T_ + kb + l4*8);
      h8 vf21 = *(const h8*)(Vbh + (size_t)(32 + l15)*T_ + kb + 32 + l4*8);
      h8 vf30 = *(const h8*)(Vbh + (size_t)(48 + l15)*T_ + kb + l4*8);
      h8 vf31 = *(const h8*)(Vbh + (size_t)(48 + l15)*T_ + kb + 32 + l4*8);

      f32x4 z = {};
      f32x4 sA[4], sB[4];
      sA[0] = MFMA16(kf1, qf01, MFMA16(kf0, qf00, z));
      sA[1] = MFMA16(kf3, qf01, MFMA16(kf2, qf00, z));
      sA[2] = MFMA16(kf5, qf01, MFMA16(kf4, qf00, z));
      sA[3] = MFMA16(kf7, qf01, MFMA16(kf6, qf00, z));
      sB[0] = MFMA16(kf1, qf11, MFMA16(kf0, qf10, z));
      sB[1] = MFMA16(kf3, qf11, MFMA16(kf2, qf10, z));
      sB[2] = MFMA16(kf5, qf11, MFMA16(kf4, qf10, z));
      sB[3] = MFMA16(kf7, qf11, MFMA16(kf6, qf10, z));

      if (kb < lastb) {        // register-prefetch next K tile
        const _Float16* kn = Kbh + (size_t)(kb + 64)*C_;
        kf0 = *(const h8*)(kn + (size_t)(     l15)*C_ + l4*8);
        kf1 = *(const h8*)(kn + (size_t)(     l15)*C_ + 32 + l4*8);
        kf2 = *(const h8*)(kn + (size_t)(16 + l15)*C_ + l4*8);
        kf3 = *(const h8*)(kn + (size_t)(16 + l15)*C_ + 32 + l4*8);
        kf4 = *(const h8*)(kn + (size_t)(32 + l15)*C_ + l4*8);
        kf5 = *(const h8*)(kn + (size_t)(32 + l15)*C_ + 32 + l4*8);
        kf6 = *(const h8*)(kn + (size_t)(48 + l15)*C_ + l4*8);
        kf7 = *(const h8*)(kn + (size_t)(48 + l15)*C_ + 32 + l4*8);
      }

      CHAIN(sA, qa, mA, lAp, accA, PlA)
      CHAIN(sB, qb, mB, lBp, accB, PlB)

      h8 paA0 = *(const h8*)(PlA + l15*72 + l4*8);
      h8 paA1 = *(const h8*)(PlA + l15*72 + 32 + l4*8);
      h8 paB0 = *(const h8*)(PlB + l15*72 + l4*8);
      h8 paB1 = *(const h8*)(PlB + l15*72 + 32 + l4*8);
      accA[0] = MFMA16(paA1, vf01, MFMA16(paA0, vf00, accA[0]));
      accA[1] = MFMA16(paA1, vf11, MFMA16(paA0, vf10, accA[1]));
      accA[2] = MFMA16(paA1, vf21, MFMA16(paA0, vf20, accA[2]));
      accA[3] = MFMA16(paA1, vf31, MFMA16(paA0, vf30, accA[3]));
      accB[0] = MFMA16(paB1, vf01, MFMA16(paB0, vf00, accB[0]));
      accB[1] = MFMA16(paB1, vf11, MFMA16(paB0, vf10, accB[1]));
      accB[2] = MFMA16(paB1, vf21, MFMA16(paB0, vf20, accB[2]));
      accB[3] = MFMA16(paB1, vf31, MFMA16(paB0, vf30, accB[3]));
    }

    // final row-sum reduce (once per tile) + normalize + store
    lAp += __shfl_xor(lAp, 16); lAp += __shfl_xor(lAp, 32);
    lBp += __shfl_xor(lBp, 16); lBp += __shfl_xor(lBp, 32);
    float lrA[4], lrB[4];
    #pragma unroll
    for (int r = 0; r < 4; r++) {
      lrA[r] = 1.f / __shfl(lAp, l4*4 + r);
      lrB[r] = 1.f / __shfl(lBp, l4*4 + r);
    }
    #pragma unroll
    for (int c2 = 0; c2 < 4; c2++) {
      #pragma unroll
      for (int r = 0; r < 4; r++) {
        float va = accA[c2][r] * lrA[r];
        float vb = accB[c2][r] * lrB[r];
        va = fminf(10.f, fmaxf(-10.f, va));
        vb = fminf(10.f, fmaxf(-10.f, vb));
        O[(size_t)(b*T_ + q0      + l4*4 + r)*C_ + h*HD + c2*16 + l15] = (_Float16)va;
        O[(size_t)(b*T_ + q0 + 16 + l4*4 + r)*C_ + h*HD + c2*16 + l15] = (_Float16)vb;
      }
    }
  }
#undef CHAIN
}

extern "C" void kernel_launch(void* const* d_in, const int* in_sizes, int n_in,
                              void* d_out, int out_size, void* d_ws, size_t ws_size,
                              hipStream_t stream) {
  (void)in_sizes; (void)n_in; (void)out_size;
  const float* x  = (const float*)d_in[0];
  const float* wq = (const float*)d_in[1];
  const float* bq = (const float*)d_in[2];
  const float* wk = (const float*)d_in[3];
  const float* bk = (const float*)d_in[4];
  const float* wv = (const float*)d_in[5];
  const float* bv = (const float*)d_in[6];
  const float* wp = (const float*)d_in[7];
  const float* bp = (const float*)d_in[8];
  float* out = (float*)d_out;

  char* ws = (char*)d_ws;
  const size_t MB = 1ull << 20;
  _Float16* qh = (_Float16*)(ws + 0*MB);    // 16 MB; attention output written in place
  _Float16* kh = (_Float16*)(ws + 16*MB);   // 16 MB
  _Float16* vh = (_Float16*)(ws + 32*MB);   // 16 MB, TRANSPOSED layout [b][h][d][t]
  _Float16* xh = (_Float16*)(ws + 48*MB);   // 16 MB (only if ws_size >= 64 MB)

  bool use_xh = ws_size >= 64*MB;
  if (use_xh) {
    cast_x_kernel<<<dim3((M_*C_/4) / 256), 256, 0, stream>>>(x, xh, M_*C_/4);
    gemm_qkv_kernel<0><<<dim3(M_/128, 24), 256, 0, stream>>>(
        xh, nullptr, wq, wk, wv, bq, bk, bv, qh, kh, vh);
  } else {
    gemm_qkv_kernel<1><<<dim3(M_/128, 24), 256, 0, stream>>>(
        nullptr, x, wq, wk, wv, bq, bk, bv, qh, kh, vh);
  }
  attn_kernel<<<dim3(2048), 64, 0, stream>>>(qh, kh, vh, qh);
  gemm_proj_kernel<<<dim3(M_/128, C_/128), 256, 0, stream>>>(qh, wp, bp, out);
}